// Round 2
// baseline (246.974 us; speedup 1.0000x reference)
//
#include <hip/hip_runtime.h>
#include <math.h>

// DSVF via exact time-domain IIR (== reference's FFT overlap-add: pole
// radius r <= 0.55 robustly, impulse response numerically dead < 64 taps).
//
// R2: latency-bound fix. OUT_BLK 128->32, WARM 128->64 => 524288 threads
// = 8 waves/SIMD (was 2). Warm-up truncation ~0.55^64 ~ 3e-17 (exact).
// Neighbor threads' warm regions are each other's output regions -> L2
// absorbs the 3x logical read amplification (R1: FETCH stayed at ideal).

#define N_PER_ROW (128 * 2048)               // 262144 samples per row
#define OUT_BLK 32                           // outputs per thread
#define WARM 64                              // warm-up samples per thread
#define BLKS_PER_ROW (N_PER_ROW / OUT_BLK)   // 8192
#define BATCH 64

__global__ __launch_bounds__(256, 8) void dsvf_iir_kernel(
    const float* __restrict__ x,
    const float* __restrict__ g_p, const float* __restrict__ R_p,
    const float* __restrict__ mhp_p, const float* __restrict__ mbp_p,
    const float* __restrict__ mlp_p,
    float* __restrict__ out)
{
    const int tid = blockIdx.x * blockDim.x + threadIdx.x;
    const int row = tid >> 13;               // / BLKS_PER_ROW (8192)
    const int blk = tid & (BLKS_PER_ROW - 1);

    // --- biquad coefficients (identical math to reference, fp32) ---
    const float g = g_p[0], R = R_p[0];
    const float m_hp = mhp_p[0], m_bp = mbp_p[0], m_lp = mlp_p[0];
    const float sig = 1.0f / (1.0f + expf(-g));
    const float gt  = tanf(1.5707963267948966f * sig);   // tan(pi*sig/2)
    const float Rt  = log1pf(expf(R));                   // softplus
    const float g2  = gt * gt;
    const float b0 = g2 * m_lp + gt * m_bp + m_hp;
    const float b1 = 2.0f * g2 * m_lp - 2.0f * m_hp;
    const float b2 = g2 * m_lp - gt * m_bp + m_hp;
    const float a0 = g2 + 2.0f * Rt * gt + 1.0f;
    const float a1 = 2.0f * g2 - 2.0f;
    const float a2 = g2 - 2.0f * Rt * gt + 1.0f;
    const float inv_a0 = 1.0f / a0;
    const float B0 = b0 * inv_a0, B1 = b1 * inv_a0, B2 = b2 * inv_a0;
    const float A1 = a1 * inv_a0, A2 = a2 * inv_a0;

    const float* __restrict__ xr = x + (size_t)row * N_PER_ROW;
    float* __restrict__ yr = out + (size_t)row * N_PER_ROW;
    const int o0 = blk * OUT_BLK;

    // Direct-form II transposed state
    float s1 = 0.0f, s2 = 0.0f;

#define STEP_D(xx) { float y_ = fmaf(B0, (xx), s1);                 \
                     s1 = fmaf(-A1, y_, fmaf(B1, (xx), s2));        \
                     s2 = fmaf(-A2, y_, B2 * (xx)); }
#define STEP_S(xx, yy) { (yy) = fmaf(B0, (xx), s1);                 \
                     s1 = fmaf(-A1, (yy), fmaf(B1, (xx), s2));      \
                     s2 = fmaf(-A2, (yy), B2 * (xx)); }

    // Warm-up (discard outputs). Row start is exactly zero state, so a
    // truncated warm-up (w = min(WARM, o0)) is exact there too. w is a
    // multiple of 32 floats -> float4-aligned.
    const int w = (o0 < WARM) ? o0 : WARM;
    const float4* wp = (const float4*)(xr + o0 - w);
    for (int i = 0; i < (w >> 2); ++i) {
        float4 v = wp[i];
        STEP_D(v.x); STEP_D(v.y); STEP_D(v.z); STEP_D(v.w);
    }

    // Emit OUT_BLK outputs, float4-vectorized load and store.
    const float4* ip = (const float4*)(xr + o0);
    float4* op = (float4*)(yr + o0);
    #pragma unroll
    for (int i = 0; i < OUT_BLK / 4; ++i) {
        float4 v = ip[i];
        float4 o;
        STEP_S(v.x, o.x); STEP_S(v.y, o.y); STEP_S(v.z, o.z); STEP_S(v.w, o.w);
        op[i] = o;
    }
#undef STEP_D
#undef STEP_S
}

extern "C" void kernel_launch(void* const* d_in, const int* in_sizes, int n_in,
                              void* d_out, int out_size, void* d_ws, size_t ws_size,
                              hipStream_t stream) {
    const float* x    = (const float*)d_in[0];
    const float* g    = (const float*)d_in[1];
    const float* R    = (const float*)d_in[2];
    const float* m_hp = (const float*)d_in[3];
    const float* m_bp = (const float*)d_in[4];
    const float* m_lp = (const float*)d_in[5];
    float* out = (float*)d_out;

    const int total_threads = BATCH * BLKS_PER_ROW;   // 524288
    dim3 block(256);
    dim3 grid(total_threads / 256);                   // 2048 blocks
    dsvf_iir_kernel<<<grid, block, 0, stream>>>(x, g, R, m_hp, m_bp, m_lp, out);
}

// Round 3
// 131.341 us; speedup vs baseline: 1.8804x; 1.8804x over previous
//
#include <hip/hip_runtime.h>
#include <math.h>

// DSVF via exact time-domain IIR (== reference's FFT overlap-add: pole
// radius r <= 0.55 robustly; impulse response numerically dead < 64 taps;
// warm-up truncation ~0.55^64 ~ 3e-17 relative).
//
// R3: coalesced-by-construction. R2's failure: per-lane streaming reads are
// uncoalesced (64 lines touched per wave load); at high occupancy L2 can't
// hide it (FETCH 6.4x ideal). Fix: LDS-staged tile. Block of 256 threads
// loads one contiguous tile (8192 out + 64 halo floats) with perfectly
// coalesced float4 loads, then each thread runs warm(64)+out(32) from LDS.
// LDS padded +1 float per 32 -> compute reads are 2 lanes/bank (free).

#define N_PER_ROW (128 * 2048)     // 262144 samples per row
#define BATCH 64
#define TPB 256
#define OUT_BLK 32                 // outputs per thread
#define WARM 64                    // warm-up samples per thread
#define TILE (TPB * OUT_BLK)       // 8192 outputs per block
#define TILES_PER_ROW (N_PER_ROW / TILE)   // 32
#define LDS_LOGICAL (TILE + WARM)  // 8256 floats
#define LDS_FLOATS (LDS_LOGICAL + (LDS_LOGICAL / 32) + 4)  // padded

__device__ __forceinline__ int padidx(int L) { return L + (L >> 5); }

__global__ __launch_bounds__(256, 4) void dsvf_iir_kernel(
    const float* __restrict__ x,
    const float* __restrict__ g_p, const float* __restrict__ R_p,
    const float* __restrict__ mhp_p, const float* __restrict__ mbp_p,
    const float* __restrict__ mlp_p,
    float* __restrict__ out)
{
    __shared__ float lds[LDS_FLOATS];

    const int b   = blockIdx.x;
    const int row = b >> 5;                  // / TILES_PER_ROW
    const int tl  = b & (TILES_PER_ROW - 1);
    const size_t base = (size_t)row * N_PER_ROW + (size_t)tl * TILE;
    const float* __restrict__ src = x + base;
    const int k = threadIdx.x;

    // --- cooperative staging: halo (64 floats) + tile (8192 floats) ---
    if (k < WARM / 4) {                       // threads 0..15 load halo
        float4 v;
        if (tl == 0) { v.x = v.y = v.z = v.w = 0.0f; }  // zero state: exact
        else         { v = *((const float4*)(src - WARM) + k); }
        float* p = &lds[padidx(4 * k)];
        p[0] = v.x; p[1] = v.y; p[2] = v.z; p[3] = v.w;
    }
    {
        const float4* sp = (const float4*)src;
        #pragma unroll
        for (int m = 0; m < TILE / 4 / TPB; ++m) {    // 8 float4 each
            const int i = k + m * TPB;
            float4 v = sp[i];
            float* p = &lds[padidx(WARM + 4 * i)];
            p[0] = v.x; p[1] = v.y; p[2] = v.z; p[3] = v.w;
        }
    }

    // --- biquad coefficients (identical math to reference, fp32) ---
    const float g = g_p[0], R = R_p[0];
    const float m_hp = mhp_p[0], m_bp = mbp_p[0], m_lp = mlp_p[0];
    const float sig = 1.0f / (1.0f + expf(-g));
    const float gt  = tanf(1.5707963267948966f * sig);   // tan(pi*sig/2)
    const float Rt  = log1pf(expf(R));                   // softplus
    const float g2  = gt * gt;
    const float b0 = g2 * m_lp + gt * m_bp + m_hp;
    const float b1 = 2.0f * g2 * m_lp - 2.0f * m_hp;
    const float b2 = g2 * m_lp - gt * m_bp + m_hp;
    const float a0 = g2 + 2.0f * Rt * gt + 1.0f;
    const float a1 = 2.0f * g2 - 2.0f;
    const float a2 = g2 - 2.0f * Rt * gt + 1.0f;
    const float inv_a0 = 1.0f / a0;
    const float B0 = b0 * inv_a0, B1 = b1 * inv_a0, B2 = b2 * inv_a0;
    const float A1 = a1 * inv_a0, A2 = a2 * inv_a0;

    __syncthreads();

    // --- per-thread IIR over LDS window [k*32, k*32 + 96) ---
    float s1 = 0.0f, s2 = 0.0f;
    const int L0 = k * OUT_BLK;               // logical window start

#define STEP_D(xx) { float y_ = fmaf(B0, (xx), s1);                 \
                     s1 = fmaf(-A1, y_, fmaf(B1, (xx), s2));        \
                     s2 = fmaf(-A2, y_, B2 * (xx)); }
#define STEP_S(xx, yy) { (yy) = fmaf(B0, (xx), s1);                 \
                     s1 = fmaf(-A1, (yy), fmaf(B1, (xx), s2));      \
                     s2 = fmaf(-A2, (yy), B2 * (xx)); }

    #pragma unroll
    for (int j = 0; j < WARM / 4; ++j) {      // 16 warm float4s
        const float* p = &lds[padidx(L0 + 4 * j)];
        STEP_D(p[0]); STEP_D(p[1]); STEP_D(p[2]); STEP_D(p[3]);
    }

    float4* op = (float4*)(out + base + (size_t)L0);
    #pragma unroll
    for (int j = 0; j < OUT_BLK / 4; ++j) {   // 8 output float4s
        const float* p = &lds[padidx(L0 + WARM + 4 * j)];
        float4 o;
        STEP_S(p[0], o.x); STEP_S(p[1], o.y); STEP_S(p[2], o.z); STEP_S(p[3], o.w);
        op[j] = o;
    }
#undef STEP_D
#undef STEP_S
}

extern "C" void kernel_launch(void* const* d_in, const int* in_sizes, int n_in,
                              void* d_out, int out_size, void* d_ws, size_t ws_size,
                              hipStream_t stream) {
    const float* x    = (const float*)d_in[0];
    const float* g    = (const float*)d_in[1];
    const float* R    = (const float*)d_in[2];
    const float* m_hp = (const float*)d_in[3];
    const float* m_bp = (const float*)d_in[4];
    const float* m_lp = (const float*)d_in[5];
    float* out = (float*)d_out;

    dim3 block(TPB);
    dim3 grid(BATCH * TILES_PER_ROW);         // 2048 blocks
    dsvf_iir_kernel<<<grid, block, 0, stream>>>(x, g, R, m_hp, m_bp, m_lp, out);
}

// Round 4
// 120.723 us; speedup vs baseline: 2.0458x; 1.0880x over previous
//
#include <hip/hip_runtime.h>
#include <math.h>

// DSVF via exact time-domain IIR (== reference's FFT overlap-add: pole
// radius r <= 0.55 robustly; impulse response numerically dead < 64 taps;
// warm-up truncation ~0.55^64 ~ 3e-17 relative).
//
// R4: coalesced STORES. R3 fixed reads via LDS staging but left per-lane
// strided stores (64 lines touched per wave store inst; L2 merge sometimes
// lost -> WRITE_SIZE spikes to 123 MB). Fix: keep 32 outputs in registers,
// barrier, scatter into the (now-dead) LDS tile, barrier, cooperative
// coalesced float4 stores (each 128-B line written once, fully).

#define N_PER_ROW (128 * 2048)     // 262144 samples per row
#define BATCH 64
#define TPB 256
#define OUT_BLK 32                 // outputs per thread
#define WARM 64                    // warm-up samples per thread
#define TILE (TPB * OUT_BLK)       // 8192 outputs per block
#define TILES_PER_ROW (N_PER_ROW / TILE)   // 32
#define LDS_LOGICAL (TILE + WARM)  // 8256 floats
#define LDS_FLOATS (LDS_LOGICAL + (LDS_LOGICAL / 32) + 4)  // padded

__device__ __forceinline__ int padidx(int L) { return L + (L >> 5); }

__global__ __launch_bounds__(256, 4) void dsvf_iir_kernel(
    const float* __restrict__ x,
    const float* __restrict__ g_p, const float* __restrict__ R_p,
    const float* __restrict__ mhp_p, const float* __restrict__ mbp_p,
    const float* __restrict__ mlp_p,
    float* __restrict__ out)
{
    __shared__ float lds[LDS_FLOATS];

    const int b   = blockIdx.x;
    const int row = b >> 5;                  // / TILES_PER_ROW
    const int tl  = b & (TILES_PER_ROW - 1);
    const size_t base = (size_t)row * N_PER_ROW + (size_t)tl * TILE;
    const float* __restrict__ src = x + base;
    const int k = threadIdx.x;

    // --- cooperative staging: halo (64 floats) + tile (8192 floats) ---
    if (k < WARM / 4) {                       // threads 0..15 load halo
        float4 v;
        if (tl == 0) { v.x = v.y = v.z = v.w = 0.0f; }  // zero state: exact
        else         { v = *((const float4*)(src - WARM) + k); }
        float* p = &lds[padidx(4 * k)];
        p[0] = v.x; p[1] = v.y; p[2] = v.z; p[3] = v.w;
    }
    {
        const float4* sp = (const float4*)src;
        #pragma unroll
        for (int m = 0; m < TILE / 4 / TPB; ++m) {    // 8 float4 each
            const int i = k + m * TPB;
            float4 v = sp[i];
            float* p = &lds[padidx(WARM + 4 * i)];
            p[0] = v.x; p[1] = v.y; p[2] = v.z; p[3] = v.w;
        }
    }

    // --- biquad coefficients (identical math to reference, fp32) ---
    const float g = g_p[0], R = R_p[0];
    const float m_hp = mhp_p[0], m_bp = mbp_p[0], m_lp = mlp_p[0];
    const float sig = 1.0f / (1.0f + expf(-g));
    const float gt  = tanf(1.5707963267948966f * sig);   // tan(pi*sig/2)
    const float Rt  = log1pf(expf(R));                   // softplus
    const float g2  = gt * gt;
    const float b0 = g2 * m_lp + gt * m_bp + m_hp;
    const float b1 = 2.0f * g2 * m_lp - 2.0f * m_hp;
    const float b2 = g2 * m_lp - gt * m_bp + m_hp;
    const float a0 = g2 + 2.0f * Rt * gt + 1.0f;
    const float a1 = 2.0f * g2 - 2.0f;
    const float a2 = g2 - 2.0f * Rt * gt + 1.0f;
    const float inv_a0 = 1.0f / a0;
    const float B0 = b0 * inv_a0, B1 = b1 * inv_a0, B2 = b2 * inv_a0;
    const float A1 = a1 * inv_a0, A2 = a2 * inv_a0;

    __syncthreads();

    // --- per-thread IIR over LDS window [k*32, k*32 + 96) (halo coords) ---
    float s1 = 0.0f, s2 = 0.0f;
    const int L0 = k * OUT_BLK;

#define STEP_D(xx) { float y_ = fmaf(B0, (xx), s1);                 \
                     s1 = fmaf(-A1, y_, fmaf(B1, (xx), s2));        \
                     s2 = fmaf(-A2, y_, B2 * (xx)); }
#define STEP_S(xx, yy) { (yy) = fmaf(B0, (xx), s1);                 \
                     s1 = fmaf(-A1, (yy), fmaf(B1, (xx), s2));      \
                     s2 = fmaf(-A2, (yy), B2 * (xx)); }

    #pragma unroll
    for (int j = 0; j < WARM / 4; ++j) {      // 16 warm float4s
        const float* p = &lds[padidx(L0 + 4 * j)];
        STEP_D(p[0]); STEP_D(p[1]); STEP_D(p[2]); STEP_D(p[3]);
    }

    float o[OUT_BLK];                         // outputs stay in VGPRs
    #pragma unroll
    for (int j = 0; j < OUT_BLK / 4; ++j) {
        const float* p = &lds[padidx(L0 + WARM + 4 * j)];
        STEP_S(p[0], o[4*j+0]); STEP_S(p[1], o[4*j+1]);
        STEP_S(p[2], o[4*j+2]); STEP_S(p[3], o[4*j+3]);
    }
#undef STEP_D
#undef STEP_S

    __syncthreads();   // all input reads done; safe to overwrite LDS

    // --- transpose-by-LDS: scatter outputs (bank (k+j)%32 -> 2-way, free) ---
    #pragma unroll
    for (int j = 0; j < OUT_BLK; ++j) {
        lds[padidx(L0 + j)] = o[j];
    }

    __syncthreads();

    // --- cooperative coalesced store: 8 float4 per thread, 1 KB/wave-inst ---
    {
        float4* dp = (float4*)(out + base);
        #pragma unroll
        for (int m = 0; m < TILE / 4 / TPB; ++m) {
            const int i = k + m * TPB;
            const float* p = &lds[padidx(4 * i)];
            float4 v;
            v.x = p[0]; v.y = p[1]; v.z = p[2]; v.w = p[3];
            dp[i] = v;
        }
    }
}

extern "C" void kernel_launch(void* const* d_in, const int* in_sizes, int n_in,
                              void* d_out, int out_size, void* d_ws, size_t ws_size,
                              hipStream_t stream) {
    const float* x    = (const float*)d_in[0];
    const float* g    = (const float*)d_in[1];
    const float* R    = (const float*)d_in[2];
    const float* m_hp = (const float*)d_in[3];
    const float* m_bp = (const float*)d_in[4];
    const float* m_lp = (const float*)d_in[5];
    float* out = (float*)d_out;

    dim3 block(TPB);
    dim3 grid(BATCH * TILES_PER_ROW);         // 2048 blocks
    dsvf_iir_kernel<<<grid, block, 0, stream>>>(x, g, R, m_hp, m_bp, m_lp, out);
}